// Round 5
// baseline (2138.854 us; speedup 1.0000x reference)
//
#include <hip/hip_runtime.h>

#define B_SZ 2048
#define HID  1024
#define G4   4096
#define IN_D 512
#define T_LEN 20

#define BM 128
#define BK 32
#define LDK 40   // padded k-stride (shorts). Reads AND writes are 16-rows-per-phase,
                 // one 16B slot -> bases 20*l15 mod 32 spread 8x2 -> <=2-way (free).

typedef __attribute__((ext_vector_type(8))) short bf16x8;
typedef __attribute__((ext_vector_type(4))) float f32x4;

__device__ __forceinline__ float bf2f(ushort u){
  union { unsigned int i; float f; } v; v.i = ((unsigned int)u) << 16; return v.f;
}
__device__ __forceinline__ ushort f2bf(float f){
  union { float f; unsigned int i; } v; v.f = f;
  unsigned int r = v.i + 0x7fffu + ((v.i >> 16) & 1u);
  return (ushort)(r >> 16);
}
__device__ __forceinline__ float rdv(const void* p, long idx, int fl){
  return fl ? ((const float*)p)[idx] : bf2f(((const ushort*)p)[idx]);
}
__device__ __forceinline__ float sigm(float x){ return 1.0f/(1.0f + __expf(-x)); }
__device__ __forceinline__ float tanh_f(float x){
  float e = __expf(2.0f*x);
  return 1.0f - 2.0f/(e + 1.0f);
}

// flag=1 -> fp32 inputs; flag=0 -> bf16. Even ushorts of LE fp32 are low mantissa
// halves -> random bf16 exponents.
__global__ void detect_dtype(const ushort* __restrict__ h0bits, int* __restrict__ flag){
  int weird = 0;
  for (int i = 0; i < 256; i += 2){
    float a = fabsf(bf2f(h0bits[i]));
    if (!(a >= 1e-8f && a <= 1e4f)) weird++;
  }
  *flag = (weird >= 32) ? 1 : 0;
}

// Canonicalize state: h0 -> (hi,lo) bf16 pair, c0 -> fp32, W_hh -> (hi,lo) bf16 pair.
__global__ void canon(const void* __restrict__ h0, const void* __restrict__ c0,
                      const void* __restrict__ whh, const int* __restrict__ flag,
                      ushort* __restrict__ hAhi, ushort* __restrict__ hAlo,
                      float* __restrict__ c_state,
                      ushort* __restrict__ whi, ushort* __restrict__ wlo){
  const int fl = *flag;
  long i = (long)blockIdx.x * 256 + threadIdx.x;
  const long N1 = (long)B_SZ * HID;
  const long N3 = (long)G4 * HID;
  if (i < N1){
    float x = rdv(h0, i, fl);
    ushort hi = f2bf(x);
    hAhi[i] = hi; hAlo[i] = f2bf(x - bf2f(hi));
    return;
  }
  i -= N1;
  if (i < N1){ c_state[i] = rdv(c0, i, fl); return; }
  i -= N1;
  if (i < N3){
    float x = rdv(whh, i, fl);
    ushort hi = f2bf(x);
    whi[i] = hi; wlo[i] = f2bf(x - bf2f(hi));
  }
}

// Fold embedding + input GEMM + biases into exact rank-2 update:
// gates_x[t,b,n] = obs[t,b,0]*M0[n] + obs[t,b,1]*M1[n] + Beff[n]
__global__ void fold_emb(const void* __restrict__ Wih, const void* __restrict__ Wemb,
                         const void* __restrict__ bemb, const void* __restrict__ bih,
                         const void* __restrict__ bhh, const int* __restrict__ flag,
                         float* __restrict__ M0, float* __restrict__ M1, float* __restrict__ Beff){
  const int n = blockIdx.x;
  const int lane = threadIdx.x;
  const int fl = *flag;
  float s0 = 0.f, s1 = 0.f, sb = 0.f;
  for (int j = lane; j < IN_D; j += 64){
    float w  = rdv(Wih, (long)n*IN_D + j, fl);
    float e0 = rdv(Wemb, 2L*j, fl);
    float e1 = rdv(Wemb, 2L*j + 1, fl);
    float be = rdv(bemb, j, fl);
    s0 += w*e0; s1 += w*e1; sb += w*be;
  }
  #pragma unroll
  for (int off = 32; off > 0; off >>= 1){
    s0 += __shfl_down(s0, off, 64);
    s1 += __shfl_down(s1, off, 64);
    sb += __shfl_down(sb, off, 64);
  }
  if (lane == 0){
    M0[n] = s0; M1[n] = s1;
    Beff[n] = sb + rdv(bih, n, fl) + rdv(bhh, n, fl);
  }
}

// Split-precision gates = h@W_hh^T: acc = h_hi*W_hi + h_lo*W_hi + h_hi*W_lo.
// A (h) staged in LDS (20 KB, conflict-free map). B (W) loaded DIRECT from global
// into registers in MFMA B-frag layout (16 rows x 64B coalesced), double-buffered,
// prefetched one k-iter ahead (48-MFMA phase covers L2 latency). No B LDS, no B
// barrier traffic.
__global__ __launch_bounds__(256, 2)
void lstm_step(const ushort* __restrict__ hin_hi, const ushort* __restrict__ hin_lo,
               ushort* __restrict__ hout_hi, ushort* __restrict__ hout_lo,
               void* __restrict__ out_final,
               float* __restrict__ c_state,
               const ushort* __restrict__ whi, const ushort* __restrict__ wlo,
               const float* __restrict__ M0, const float* __restrict__ M1,
               const float* __restrict__ Beff,
               const void* __restrict__ obs_raw, int t_step,
               const int* __restrict__ flag, int is_final)
{
  __shared__ ushort ldsAhi[BM * LDK];        // 10,240 B
  __shared__ ushort ldsAlo[BM * LDK];        // 10,240 B

  const int tid  = threadIdx.x;
  const int wave = tid >> 6;
  const int lane = tid & 63;
  const int l15  = lane & 15;
  const int quad = lane >> 4;
  const int wm   = wave & 1;    // M half (64 rows)
  const int wn   = wave >> 1;   // N half (16 cols of each gate)

  const int bid  = blockIdx.x;
  const int bm_0 = (bid >> 5) * BM;                            // 16 M-blocks
  const int n0   = (((bid & 7) << 2) | ((bid >> 3) & 3)) * 32; // 32 N-blocks, XCD-grouped

  f32x4 acc[4][4];   // [gate][mt]
  #pragma unroll
  for (int g = 0; g < 4; g++)
    #pragma unroll
    for (int mt = 0; mt < 4; mt++)
      acc[g][mt] = (f32x4){0.f, 0.f, 0.f, 0.f};

  // ---- A staging map: row = wave*16 + l15 (+64), slot = quad (16B) ----
  const int rA = wave*16 + l15;
  const int cA = quad*8;                       // shorts
  const size_t aOff1 = (size_t)(bm_0 + rA)*HID + cA;
  const size_t aOff2 = aOff1 + (size_t)64*HID;
  const int lw1 = rA*LDK + cA;
  const int lw2 = (rA + 64)*LDK + cA;

  // ---- B direct-load bases: W row = g*HID + n0 + wn*16 + l15, k-chunk quad*8 ----
  const ushort* bHi[4]; const ushort* bLo[4];
  #pragma unroll
  for (int g = 0; g < 4; g++) {
    const size_t row = (size_t)(g*HID + n0 + wn*16 + l15);
    bHi[g] = whi + row*HID + quad*8;
    bLo[g] = wlo + row*HID + quad*8;
  }

  uint4 pAh1, pAl1, pAh2, pAl2;
  uint4 Bb0[8], Bb1[8];   // [0..3]=hi gates, [4..7]=lo gates

  // preload k=0
  pAh1 = *reinterpret_cast<const uint4*>(hin_hi + aOff1);
  pAl1 = *reinterpret_cast<const uint4*>(hin_lo + aOff1);
  pAh2 = *reinterpret_cast<const uint4*>(hin_hi + aOff2);
  pAl2 = *reinterpret_cast<const uint4*>(hin_lo + aOff2);
  #pragma unroll
  for (int g = 0; g < 4; g++) {
    Bb0[g]   = *reinterpret_cast<const uint4*>(bHi[g]);
    Bb0[4+g] = *reinterpret_cast<const uint4*>(bLo[g]);
  }

  const int aRow = wm*64 + l15;
  const int kof  = quad*8;

  auto body = [&](int kt, uint4* Bc, uint4* Bn) {
    __syncthreads();   // readers of previous A tile done
    *reinterpret_cast<uint4*>(&ldsAhi[lw1]) = pAh1;
    *reinterpret_cast<uint4*>(&ldsAlo[lw1]) = pAl1;
    *reinterpret_cast<uint4*>(&ldsAhi[lw2]) = pAh2;
    *reinterpret_cast<uint4*>(&ldsAlo[lw2]) = pAl2;
    __syncthreads();   // A tile visible

    if (kt + 1 < HID/BK) {
      const int k1 = (kt + 1)*BK;
      pAh1 = *reinterpret_cast<const uint4*>(hin_hi + aOff1 + k1);
      pAl1 = *reinterpret_cast<const uint4*>(hin_lo + aOff1 + k1);
      pAh2 = *reinterpret_cast<const uint4*>(hin_hi + aOff2 + k1);
      pAl2 = *reinterpret_cast<const uint4*>(hin_lo + aOff2 + k1);
      #pragma unroll
      for (int g = 0; g < 4; g++) {
        Bn[g]   = *reinterpret_cast<const uint4*>(bHi[g] + k1);
        Bn[4+g] = *reinterpret_cast<const uint4*>(bLo[g] + k1);
      }
    }

    bf16x8 ah[4], al[4];
    #pragma unroll
    for (int mt = 0; mt < 4; mt++) {
      ah[mt] = *reinterpret_cast<const bf16x8*>(&ldsAhi[(aRow + mt*16)*LDK + kof]);
      al[mt] = *reinterpret_cast<const bf16x8*>(&ldsAlo[(aRow + mt*16)*LDK + kof]);
    }
    #pragma unroll
    for (int g = 0; g < 4; g++) {
      const bf16x8 bh = __builtin_bit_cast(bf16x8, Bc[g]);
      #pragma unroll
      for (int mt = 0; mt < 4; mt++)
        acc[g][mt] = __builtin_amdgcn_mfma_f32_16x16x32_bf16(ah[mt], bh, acc[g][mt], 0, 0, 0);
    }
    #pragma unroll
    for (int g = 0; g < 4; g++) {
      const bf16x8 bh = __builtin_bit_cast(bf16x8, Bc[g]);
      #pragma unroll
      for (int mt = 0; mt < 4; mt++)
        acc[g][mt] = __builtin_amdgcn_mfma_f32_16x16x32_bf16(al[mt], bh, acc[g][mt], 0, 0, 0);
    }
    #pragma unroll
    for (int g = 0; g < 4; g++) {
      const bf16x8 bl = __builtin_bit_cast(bf16x8, Bc[4+g]);
      #pragma unroll
      for (int mt = 0; mt < 4; mt++)
        acc[g][mt] = __builtin_amdgcn_mfma_f32_16x16x32_bf16(ah[mt], bl, acc[g][mt], 0, 0, 0);
    }
  };

  #pragma unroll 1
  for (int k2 = 0; k2 < (HID/BK)/2; k2++) {
    body(2*k2,     Bb0, Bb1);
    body(2*k2 + 1, Bb1, Bb0);
  }

  // Epilogue: fused LSTM cell. C/D layout: col = lane&15, row = quad*4 + reg.
  const int fl = *flag;
  const int j = n0 + wn*16 + l15;
  float bi[4], m0v[4], m1v[4];
  #pragma unroll
  for (int g = 0; g < 4; g++) {
    bi[g]  = Beff[g*HID + j];
    m0v[g] = M0[g*HID + j];
    m1v[g] = M1[g*HID + j];
  }
  #pragma unroll
  for (int mt = 0; mt < 4; mt++) {
    #pragma unroll
    for (int r = 0; r < 4; r++) {
      const int b = bm_0 + wm*64 + mt*16 + quad*4 + r;
      const long oidx = ((long)t_step * B_SZ + b) * 2;
      const float o0 = rdv(obs_raw, oidx, fl);
      const float o1 = rdv(obs_raw, oidx + 1, fl);
      const size_t off = (size_t)b*HID + j;
      float pi = acc[0][mt][r] + o0*m0v[0] + o1*m1v[0] + bi[0];
      float pf = acc[1][mt][r] + o0*m0v[1] + o1*m1v[1] + bi[1];
      float pg = acc[2][mt][r] + o0*m0v[2] + o1*m1v[2] + bi[2];
      float po = acc[3][mt][r] + o0*m0v[3] + o1*m1v[3] + bi[3];
      float cn = sigm(pf)*c_state[off] + sigm(pi)*tanh_f(pg);
      float hn = sigm(po)*tanh_f(cn);
      c_state[off] = cn;
      if (is_final) {
        if (fl) ((float*)out_final)[off] = hn;
        else    ((ushort*)out_final)[off] = f2bf(hn);
      } else {
        ushort hi = f2bf(hn);
        hout_hi[off] = hi;
        hout_lo[off] = f2bf(hn - bf2f(hi));
      }
    }
  }
}

extern "C" void kernel_launch(void* const* d_in, const int* in_sizes, int n_in,
                              void* d_out, int out_size, void* d_ws, size_t ws_size,
                              hipStream_t stream) {
  const void* obs  = d_in[0];
  const void* h0   = d_in[1];
  const void* c0   = d_in[2];
  const void* Wemb = d_in[3];
  const void* bemb = d_in[4];
  const void* Wih  = d_in[5];
  const void* Whh  = d_in[6];
  const void* bih  = d_in[7];
  const void* bhh  = d_in[8];

  char* w = (char*)d_ws;
  int*    flag    = (int*)w;
  float*  M0      = (float*)(w + 256);
  float*  M1      = M0 + G4;
  float*  Beff    = M1 + G4;
  float*  c_state = Beff + G4;                              // 8 MB
  ushort* whi     = (ushort*)(c_state + (size_t)B_SZ*HID);  // 8 MB
  ushort* wlo     = whi + (size_t)G4*HID;                   // 8 MB
  ushort* hAhi    = wlo + (size_t)G4*HID;                   // 4 MB
  ushort* hAlo    = hAhi + (size_t)B_SZ*HID;                // 4 MB
  ushort* hBhi    = hAlo + (size_t)B_SZ*HID;                // 4 MB
  ushort* hBlo    = hBhi + (size_t)B_SZ*HID;                // 4 MB

  detect_dtype<<<1, 1, 0, stream>>>((const ushort*)h0, flag);

  long totalCanon = 2L*B_SZ*HID + (long)G4*HID;
  canon<<<(int)((totalCanon + 255)/256), 256, 0, stream>>>(
      h0, c0, Whh, flag, hAhi, hAlo, c_state, whi, wlo);

  fold_emb<<<G4, 64, 0, stream>>>(Wih, Wemb, bemb, bih, bhh, flag, M0, M1, Beff);

  for (int t = 0; t < T_LEN; t++) {
    const ushort* ih = (t & 1) ? hBhi : hAhi;
    const ushort* il = (t & 1) ? hBlo : hAlo;
    ushort* oh = (t & 1) ? hAhi : hBhi;
    ushort* ol = (t & 1) ? hAlo : hBlo;
    lstm_step<<<512, 256, 0, stream>>>(ih, il, oh, ol, d_out, c_state,
                                       whi, wlo, M0, M1, Beff,
                                       obs, t, flag, (t == T_LEN - 1) ? 1 : 0);
  }
}

// Round 6
// 1369.993 us; speedup vs baseline: 1.5612x; 1.5612x over previous
//
#include <hip/hip_runtime.h>

#define B_SZ 2048
#define HID  1024
#define G4   4096
#define IN_D 512
#define T_LEN 20

#define BM 128
#define BK 32
#define LDK 40   // padded k-stride (shorts): reads & writes 16-rows/phase, one 16B slot
                 // -> 20*r mod 32 spans all banks 2-way max (free per m136)

typedef __attribute__((ext_vector_type(8))) short bf16x8;
typedef __attribute__((ext_vector_type(4))) float f32x4;

__device__ __forceinline__ float bf2f(ushort u){
  union { unsigned int i; float f; } v; v.i = ((unsigned int)u) << 16; return v.f;
}
__device__ __forceinline__ ushort f2bf(float f){
  union { float f; unsigned int i; } v; v.f = f;
  unsigned int r = v.i + 0x7fffu + ((v.i >> 16) & 1u);
  return (ushort)(r >> 16);
}
__device__ __forceinline__ float rdv(const void* p, long idx, int fl){
  return fl ? ((const float*)p)[idx] : bf2f(((const ushort*)p)[idx]);
}
__device__ __forceinline__ float sigm(float x){ return 1.0f/(1.0f + __expf(-x)); }
__device__ __forceinline__ float tanh_f(float x){
  float e = __expf(2.0f*x);
  return 1.0f - 2.0f/(e + 1.0f);
}

// flag=1 -> fp32 inputs; flag=0 -> bf16. Even ushorts of LE fp32 are low mantissa
// halves -> random bf16 exponents.
__global__ void detect_dtype(const ushort* __restrict__ h0bits, int* __restrict__ flag){
  int weird = 0;
  for (int i = 0; i < 256; i += 2){
    float a = fabsf(bf2f(h0bits[i]));
    if (!(a >= 1e-8f && a <= 1e4f)) weird++;
  }
  *flag = (weird >= 32) ? 1 : 0;
}

// Packed layouts (both make every wave-level load a dense 1KB span):
//   W:  wpk[((nb*32+kt)*2+s)*4096 + r*32 + kk]   nb=j>>5, kt=k>>5, s=hi/lo,
//       r=g*32+(j&31), kk=k&31          (16 MB total, replaces whi/wlo)
//   h:  hpk[(mb*32+kt)*4096 + r*32 + kk]         mb=b>>7, r=b&127, kt=j>>5, kk=j&31
__global__ void canon(const void* __restrict__ h0, const void* __restrict__ c0,
                      const void* __restrict__ whh, const int* __restrict__ flag,
                      ushort* __restrict__ hAhi, ushort* __restrict__ hAlo,
                      float* __restrict__ c_state,
                      ushort* __restrict__ wpk){
  const int fl = *flag;
  long i = (long)blockIdx.x * 256 + threadIdx.x;
  const long N1 = (long)B_SZ * HID;
  const long N3 = (long)G4 * HID;
  if (i < N1){
    const int b = (int)(i >> 10), j = (int)(i & 1023);
    const long po = ((long)(b >> 7)*32 + (j >> 5))*4096 + (b & 127)*32 + (j & 31);
    float x = rdv(h0, i, fl);
    ushort hi = f2bf(x);
    hAhi[po] = hi; hAlo[po] = f2bf(x - bf2f(hi));
    return;
  }
  i -= N1;
  if (i < N1){ c_state[i] = rdv(c0, i, fl); return; }
  i -= N1;
  if (i < N3){
    const int n = (int)(i >> 10), k = (int)(i & 1023);
    const int g = n >> 10, j = n & 1023;
    const int nb = j >> 5, r = g*32 + (j & 31);
    const int kt = k >> 5, kk = k & 31;
    const long base = ((long)(nb*32 + kt)*2)*4096 + r*32 + kk;
    float x = rdv(whh, i, fl);
    ushort hi = f2bf(x);
    wpk[base] = hi; wpk[base + 4096] = f2bf(x - bf2f(hi));
  }
}

// Fold embedding + input GEMM + biases into exact rank-2 update:
// gates_x[t,b,n] = obs[t,b,0]*M0[n] + obs[t,b,1]*M1[n] + Beff[n]
__global__ void fold_emb(const void* __restrict__ Wih, const void* __restrict__ Wemb,
                         const void* __restrict__ bemb, const void* __restrict__ bih,
                         const void* __restrict__ bhh, const int* __restrict__ flag,
                         float* __restrict__ M0, float* __restrict__ M1, float* __restrict__ Beff){
  const int n = blockIdx.x;
  const int lane = threadIdx.x;
  const int fl = *flag;
  float s0 = 0.f, s1 = 0.f, sb = 0.f;
  for (int j = lane; j < IN_D; j += 64){
    float w  = rdv(Wih, (long)n*IN_D + j, fl);
    float e0 = rdv(Wemb, 2L*j, fl);
    float e1 = rdv(Wemb, 2L*j + 1, fl);
    float be = rdv(bemb, j, fl);
    s0 += w*e0; s1 += w*e1; sb += w*be;
  }
  #pragma unroll
  for (int off = 32; off > 0; off >>= 1){
    s0 += __shfl_down(s0, off, 64);
    s1 += __shfl_down(s1, off, 64);
    sb += __shfl_down(sb, off, 64);
  }
  if (lane == 0){
    M0[n] = s0; M1[n] = s1;
    Beff[n] = sb + rdv(bih, n, fl) + rdv(bhh, n, fl);
  }
}

// Split-precision gates = h@W_hh^T: acc = h_hi*W_hi + h_lo*W_hi + h_hi*W_lo.
// A (h) via LDS (20 KB, conflict-free, dense packed global reads). B (W) DIRECT
// from packed global into B-frag registers (dense 1KB spans), double-buffered,
// prefetched one iter ahead so the 48-MFMA phase covers L2 latency.
__global__ __launch_bounds__(256, 2)
void lstm_step(const ushort* __restrict__ hin_hi, const ushort* __restrict__ hin_lo,
               ushort* __restrict__ hout_hi, ushort* __restrict__ hout_lo,
               void* __restrict__ out_final,
               float* __restrict__ c_state,
               const ushort* __restrict__ wpk,
               const float* __restrict__ M0, const float* __restrict__ M1,
               const float* __restrict__ Beff,
               const void* __restrict__ obs_raw, int t_step,
               const int* __restrict__ flag, int is_final)
{
  __shared__ ushort ldsAhi[BM * LDK];        // 10,240 B
  __shared__ ushort ldsAlo[BM * LDK];        // 10,240 B

  const int tid  = threadIdx.x;
  const int wave = tid >> 6;
  const int lane = tid & 63;
  const int l15  = lane & 15;
  const int quad = lane >> 4;
  const int wm   = wave & 1;    // M half (64 rows)
  const int wn   = wave >> 1;   // N half (16 cols of each gate)

  const int bid  = blockIdx.x;
  const int mb   = bid >> 5;                                 // 16 M-blocks
  const int bm_0 = mb * BM;
  const int n0   = (((bid & 7) << 2) | ((bid >> 3) & 3)) * 32; // XCD-grouped N
  const int nb   = n0 >> 5;

  f32x4 acc[4][4];   // [gate][mt]
  #pragma unroll
  for (int g = 0; g < 4; g++)
    #pragma unroll
    for (int mt = 0; mt < 4; mt++)
      acc[g][mt] = (f32x4){0.f, 0.f, 0.f, 0.f};

  // ---- A: packed-tile offsets. Thread stages rows r and r+64, slot quad ----
  const int rA  = wave*16 + l15;
  const int oA1 = rA*32 + quad*8;            // within 4096-short k-tile
  const int oA2 = oA1 + 64*32;
  const ushort* aBaseHi = hin_hi + (size_t)mb*32*4096;
  const ushort* aBaseLo = hin_lo + (size_t)mb*32*4096;
  const int lw1 = rA*LDK + quad*8;
  const int lw2 = (rA + 64)*LDK + quad*8;

  // ---- B: direct frag loads from packed W; per-gate lane offsets ----
  const ushort* wBase = wpk + (size_t)nb*32*8192;
  int lB[4];
  #pragma unroll
  for (int g = 0; g < 4; g++)
    lB[g] = (g*32 + wn*16 + l15)*32 + quad*8;

  uint4 pAh1, pAl1, pAh2, pAl2;
  uint4 Bb0[8], Bb1[8];   // [0..3]=hi gates, [4..7]=lo gates

  // preload kt=0
  pAh1 = *reinterpret_cast<const uint4*>(aBaseHi + oA1);
  pAl1 = *reinterpret_cast<const uint4*>(aBaseLo + oA1);
  pAh2 = *reinterpret_cast<const uint4*>(aBaseHi + oA2);
  pAl2 = *reinterpret_cast<const uint4*>(aBaseLo + oA2);
  #pragma unroll
  for (int g = 0; g < 4; g++) {
    Bb0[g]   = *reinterpret_cast<const uint4*>(wBase + lB[g]);
    Bb0[4+g] = *reinterpret_cast<const uint4*>(wBase + 4096 + lB[g]);
  }

  const int aRow = wm*64 + l15;
  const int kof  = quad*8;

  auto body = [&](int kt, uint4* Bc, uint4* Bn) {
    __syncthreads();   // readers of previous A tile done
    *reinterpret_cast<uint4*>(&ldsAhi[lw1]) = pAh1;
    *reinterpret_cast<uint4*>(&ldsAlo[lw1]) = pAl1;
    *reinterpret_cast<uint4*>(&ldsAhi[lw2]) = pAh2;
    *reinterpret_cast<uint4*>(&ldsAlo[lw2]) = pAl2;
    __syncthreads();   // A tile visible

    if (kt + 1 < HID/BK) {
      const ushort* aHi = aBaseHi + (kt + 1)*4096;
      const ushort* aLo = aBaseLo + (kt + 1)*4096;
      pAh1 = *reinterpret_cast<const uint4*>(aHi + oA1);
      pAl1 = *reinterpret_cast<const uint4*>(aLo + oA1);
      pAh2 = *reinterpret_cast<const uint4*>(aHi + oA2);
      pAl2 = *reinterpret_cast<const uint4*>(aLo + oA2);
      const ushort* wB = wBase + (size_t)(kt + 1)*8192;
      #pragma unroll
      for (int g = 0; g < 4; g++) {
        Bn[g]   = *reinterpret_cast<const uint4*>(wB + lB[g]);
        Bn[4+g] = *reinterpret_cast<const uint4*>(wB + 4096 + lB[g]);
      }
    }

    bf16x8 ah[4], al[4];
    #pragma unroll
    for (int mt = 0; mt < 4; mt++) {
      ah[mt] = *reinterpret_cast<const bf16x8*>(&ldsAhi[(aRow + mt*16)*LDK + kof]);
      al[mt] = *reinterpret_cast<const bf16x8*>(&ldsAlo[(aRow + mt*16)*LDK + kof]);
    }
    #pragma unroll
    for (int g = 0; g < 4; g++) {
      const bf16x8 bh = __builtin_bit_cast(bf16x8, Bc[g]);
      #pragma unroll
      for (int mt = 0; mt < 4; mt++)
        acc[g][mt] = __builtin_amdgcn_mfma_f32_16x16x32_bf16(ah[mt], bh, acc[g][mt], 0, 0, 0);
    }
    #pragma unroll
    for (int g = 0; g < 4; g++) {
      const bf16x8 bh = __builtin_bit_cast(bf16x8, Bc[g]);
      #pragma unroll
      for (int mt = 0; mt < 4; mt++)
        acc[g][mt] = __builtin_amdgcn_mfma_f32_16x16x32_bf16(al[mt], bh, acc[g][mt], 0, 0, 0);
    }
    #pragma unroll
    for (int g = 0; g < 4; g++) {
      const bf16x8 bl = __builtin_bit_cast(bf16x8, Bc[4+g]);
      #pragma unroll
      for (int mt = 0; mt < 4; mt++)
        acc[g][mt] = __builtin_amdgcn_mfma_f32_16x16x32_bf16(ah[mt], bl, acc[g][mt], 0, 0, 0);
    }
  };

  #pragma unroll 1
  for (int k2 = 0; k2 < (HID/BK)/2; k2++) {
    body(2*k2,     Bb0, Bb1);
    body(2*k2 + 1, Bb1, Bb0);
  }

  // Epilogue: fused LSTM cell. C/D layout: col = lane&15, row = quad*4 + reg.
  const int fl = *flag;
  const int j = n0 + wn*16 + l15;
  float bi[4], m0v[4], m1v[4];
  #pragma unroll
  for (int g = 0; g < 4; g++) {
    bi[g]  = Beff[g*HID + j];
    m0v[g] = M0[g*HID + j];
    m1v[g] = M1[g*HID + j];
  }
  #pragma unroll
  for (int mt = 0; mt < 4; mt++) {
    #pragma unroll
    for (int r = 0; r < 4; r++) {
      const int bl7 = wm*64 + mt*16 + quad*4 + r;   // b & 127
      const int b   = bm_0 + bl7;
      const long oidx = ((long)t_step * B_SZ + b) * 2;
      const float o0 = rdv(obs_raw, oidx, fl);
      const float o1 = rdv(obs_raw, oidx + 1, fl);
      const size_t off = (size_t)b*HID + j;
      float pi = acc[0][mt][r] + o0*m0v[0] + o1*m1v[0] + bi[0];
      float pf = acc[1][mt][r] + o0*m0v[1] + o1*m1v[1] + bi[1];
      float pg = acc[2][mt][r] + o0*m0v[2] + o1*m1v[2] + bi[2];
      float po = acc[3][mt][r] + o0*m0v[3] + o1*m1v[3] + bi[3];
      float cn = sigm(pf)*c_state[off] + sigm(pi)*tanh_f(pg);
      float hn = sigm(po)*tanh_f(cn);
      c_state[off] = cn;
      if (is_final) {
        if (fl) ((float*)out_final)[off] = hn;
        else    ((ushort*)out_final)[off] = f2bf(hn);
      } else {
        // packed h for next step: (mb*32 + j>>5)*4096 + (b&127)*32 + (j&31)
        const long hpo = ((long)mb*32 + nb)*4096 + bl7*32 + (wn*16 + l15);
        ushort hi = f2bf(hn);
        hout_hi[hpo] = hi;
        hout_lo[hpo] = f2bf(hn - bf2f(hi));
      }
    }
  }
}

extern "C" void kernel_launch(void* const* d_in, const int* in_sizes, int n_in,
                              void* d_out, int out_size, void* d_ws, size_t ws_size,
                              hipStream_t stream) {
  const void* obs  = d_in[0];
  const void* h0   = d_in[1];
  const void* c0   = d_in[2];
  const void* Wemb = d_in[3];
  const void* bemb = d_in[4];
  const void* Wih  = d_in[5];
  const void* Whh  = d_in[6];
  const void* bih  = d_in[7];
  const void* bhh  = d_in[8];

  char* w = (char*)d_ws;
  int*    flag    = (int*)w;
  float*  M0      = (float*)(w + 256);
  float*  M1      = M0 + G4;
  float*  Beff    = M1 + G4;
  float*  c_state = Beff + G4;                              // 8 MB
  ushort* wpk     = (ushort*)(c_state + (size_t)B_SZ*HID);  // 16 MB packed W (hi+lo)
  ushort* hAhi    = wpk + 2L*G4*HID;                        // 4 MB
  ushort* hAlo    = hAhi + (size_t)B_SZ*HID;                // 4 MB
  ushort* hBhi    = hAlo + (size_t)B_SZ*HID;                // 4 MB
  ushort* hBlo    = hBhi + (size_t)B_SZ*HID;                // 4 MB  (~40 MB total)

  detect_dtype<<<1, 1, 0, stream>>>((const ushort*)h0, flag);

  long totalCanon = 2L*B_SZ*HID + (long)G4*HID;
  canon<<<(int)((totalCanon + 255)/256), 256, 0, stream>>>(
      h0, c0, Whh, flag, hAhi, hAlo, c_state, wpk);

  fold_emb<<<G4, 64, 0, stream>>>(Wih, Wemb, bemb, bih, bhh, flag, M0, M1, Beff);

  for (int t = 0; t < T_LEN; t++) {
    const ushort* ih = (t & 1) ? hBhi : hAhi;
    const ushort* il = (t & 1) ? hBlo : hAlo;
    ushort* oh = (t & 1) ? hAhi : hBhi;
    ushort* ol = (t & 1) ? hAlo : hBlo;
    lstm_step<<<512, 256, 0, stream>>>(ih, il, oh, ol, d_out, c_state,
                                       wpk, M0, M1, Beff,
                                       obs, t, flag, (t == T_LEN - 1) ? 1 : 0);
  }
}

// Round 7
// 1096.313 us; speedup vs baseline: 1.9510x; 1.2496x over previous
//
#include <hip/hip_runtime.h>

#define B_SZ 2048
#define HID  1024
#define G4   4096
#define IN_D 512
#define T_LEN 20
#define BM 128
#define BK 32

// Swizzled offset of element (row r, k-chunk q) inside a 128x32 packed tile.
// 16B chunk q stored at position q ^ ((r>>1)&3): per 16-lane phase the b128
// frag reads land on 8 banks x 2-way (free, m136); DMA writes stay linear.
#define POFF(r, q) ((r)*32 + ((((q) ^ (((r) >> 1) & 3))) << 3))

typedef __attribute__((ext_vector_type(8))) short bf16x8;
typedef __attribute__((ext_vector_type(4))) float f32x4;
typedef const __attribute__((address_space(1))) void* gas_p;
typedef __attribute__((address_space(3))) void* las_p;

__device__ __forceinline__ float bf2f(ushort u){
  union { unsigned int i; float f; } v; v.i = ((unsigned int)u) << 16; return v.f;
}
__device__ __forceinline__ ushort f2bf(float f){
  union { float f; unsigned int i; } v; v.f = f;
  unsigned int r = v.i + 0x7fffu + ((v.i >> 16) & 1u);
  return (ushort)(r >> 16);
}
__device__ __forceinline__ float rdv(const void* p, long idx, int fl){
  return fl ? ((const float*)p)[idx] : bf2f(((const ushort*)p)[idx]);
}
__device__ __forceinline__ float sigm(float x){ return 1.0f/(1.0f + __expf(-x)); }
__device__ __forceinline__ float tanh_f(float x){
  float e = __expf(2.0f*x);
  return 1.0f - 2.0f/(e + 1.0f);
}

// flag=1 -> fp32 inputs; flag=0 -> bf16. Even ushorts of LE fp32 are low mantissa
// halves -> random bf16 exponents.
__global__ void detect_dtype(const ushort* __restrict__ h0bits, int* __restrict__ flag){
  int weird = 0;
  for (int i = 0; i < 256; i += 2){
    float a = fabsf(bf2f(h0bits[i]));
    if (!(a >= 1e-8f && a <= 1e4f)) weird++;
  }
  *flag = (weird >= 32) ? 1 : 0;
}

// Packed+swizzled layouts (every wave-level access = dense 1KB span; frag reads 2-way max):
//   h: tile (mb*32+kt) of 4096 shorts, element (b&127, j&31) at POFF
//   W: tiles (nb*32+kt)*2 {hi,lo} of 4096 shorts, row r = g*32+(j&31)
__global__ void canon(const void* __restrict__ h0, const void* __restrict__ c0,
                      const void* __restrict__ whh, const int* __restrict__ flag,
                      ushort* __restrict__ hAhi, ushort* __restrict__ hAlo,
                      float* __restrict__ c_state,
                      ushort* __restrict__ wpk){
  const int fl = *flag;
  long i = (long)blockIdx.x * 256 + threadIdx.x;
  const long N1 = (long)B_SZ * HID;
  const long N3 = (long)G4 * HID;
  if (i < N1){
    const int b = (int)(i >> 10), j = (int)(i & 1023);
    const int r = b & 127, q = (j >> 3) & 3;
    const long po = ((long)(b >> 7)*32 + (j >> 5))*4096 + POFF(r, q) + (j & 7);
    float x = rdv(h0, i, fl);
    ushort hi = f2bf(x);
    hAhi[po] = hi; hAlo[po] = f2bf(x - bf2f(hi));
    return;
  }
  i -= N1;
  if (i < N1){ c_state[i] = rdv(c0, i, fl); return; }
  i -= N1;
  if (i < N3){
    const int n = (int)(i >> 10), k = (int)(i & 1023);
    const int g = n >> 10, j = n & 1023;
    const int nb = j >> 5, r = g*32 + (j & 31);
    const int kt = k >> 5, q = (k >> 3) & 3;
    const long base = ((long)(nb*32 + kt)*2)*4096 + POFF(r, q) + (k & 7);
    float x = rdv(whh, i, fl);
    ushort hi = f2bf(x);
    wpk[base] = hi; wpk[base + 4096] = f2bf(x - bf2f(hi));
  }
}

// Fold embedding + input GEMM + biases into exact rank-2 update:
// gates_x[t,b,n] = obs[t,b,0]*M0[n] + obs[t,b,1]*M1[n] + Beff[n]
__global__ void fold_emb(const void* __restrict__ Wih, const void* __restrict__ Wemb,
                         const void* __restrict__ bemb, const void* __restrict__ bih,
                         const void* __restrict__ bhh, const int* __restrict__ flag,
                         float* __restrict__ M0, float* __restrict__ M1, float* __restrict__ Beff){
  const int n = blockIdx.x;
  const int lane = threadIdx.x;
  const int fl = *flag;
  float s0 = 0.f, s1 = 0.f, sb = 0.f;
  for (int j = lane; j < IN_D; j += 64){
    float w  = rdv(Wih, (long)n*IN_D + j, fl);
    float e0 = rdv(Wemb, 2L*j, fl);
    float e1 = rdv(Wemb, 2L*j + 1, fl);
    float be = rdv(bemb, j, fl);
    s0 += w*e0; s1 += w*e1; sb += w*be;
  }
  #pragma unroll
  for (int off = 32; off > 0; off >>= 1){
    s0 += __shfl_down(s0, off, 64);
    s1 += __shfl_down(s1, off, 64);
    sb += __shfl_down(sb, off, 64);
  }
  if (lane == 0){
    M0[n] = s0; M1[n] = s1;
    Beff[n] = sb + rdv(bih, n, fl) + rdv(bhh, n, fl);
  }
}

// Split-precision gates = h@W_hh^T: acc = h_hi*W_hi + h_lo*W_hi + h_hi*W_lo.
// A and B both DMA'd to LDS via global_load_lds width=16 (no staging VGPRs,
// issue point fixed), double-buffered, ONE barrier per k-iter: the barrier's
// vmcnt(0) drain doubles as the DMA completion wait for the tile issued one
// full compute phase earlier.
__global__ __launch_bounds__(256, 2)
void lstm_step(const ushort* __restrict__ hin_hi, const ushort* __restrict__ hin_lo,
               ushort* __restrict__ hout_hi, ushort* __restrict__ hout_lo,
               void* __restrict__ out_final,
               float* __restrict__ c_state,
               const ushort* __restrict__ wpk,
               const float* __restrict__ M0, const float* __restrict__ M1,
               const float* __restrict__ Beff,
               const void* __restrict__ obs_raw, int t_step,
               const int* __restrict__ flag, int is_final)
{
  // [buf][region][4096]: regions 0=Ahi 1=Alo 2=Bhi 3=Blo; 64 KB total
  __shared__ __align__(16) ushort lds[2*4*4096];

  const int tid  = threadIdx.x;
  const int wave = tid >> 6;
  const int lane = tid & 63;
  const int l15  = lane & 15;
  const int quad = lane >> 4;
  const int wm   = wave & 1;    // M half (64 rows)
  const int wn   = wave >> 1;   // N half (16 cols of each gate)

  const int bid  = blockIdx.x;
  const int mb   = bid >> 5;                                   // 16 M-blocks
  const int n0   = (((bid & 7) << 2) | ((bid >> 3) & 3)) * 32; // XCD-grouped N
  const int nb   = n0 >> 5;

  f32x4 acc[4][4];
  #pragma unroll
  for (int g = 0; g < 4; g++)
    #pragma unroll
    for (int mt = 0; mt < 4; mt++)
      acc[g][mt] = (f32x4){0.f, 0.f, 0.f, 0.f};

  const ushort* aHiB = hin_hi + (size_t)mb*32*4096;
  const ushort* aLoB = hin_lo + (size_t)mb*32*4096;
  const ushort* wB   = wpk + (size_t)nb*32*8192;

  const int dOff1 = wave*512 + lane*8;   // shorts: slot 'wave' of 8x1KB region
  const int dOff2 = dOff1 + 2048;        // slot wave+4

  #define DMA_TILE(kt, buf) do {                                              \
    const ushort* s0 = aHiB + (kt)*4096;                                      \
    const ushort* s1 = aLoB + (kt)*4096;                                      \
    const ushort* s2 = wB + (size_t)(kt)*8192;                                \
    const ushort* s3 = s2 + 4096;                                             \
    ushort* d = &lds[(buf)*16384];                                            \
    __builtin_amdgcn_global_load_lds((gas_p)(s0+dOff1), (las_p)(d+dOff1),       16,0,0); \
    __builtin_amdgcn_global_load_lds((gas_p)(s0+dOff2), (las_p)(d+dOff2),       16,0,0); \
    __builtin_amdgcn_global_load_lds((gas_p)(s1+dOff1), (las_p)(d+4096+dOff1),  16,0,0); \
    __builtin_amdgcn_global_load_lds((gas_p)(s1+dOff2), (las_p)(d+4096+dOff2),  16,0,0); \
    __builtin_amdgcn_global_load_lds((gas_p)(s2+dOff1), (las_p)(d+8192+dOff1),  16,0,0); \
    __builtin_amdgcn_global_load_lds((gas_p)(s2+dOff2), (las_p)(d+8192+dOff2),  16,0,0); \
    __builtin_amdgcn_global_load_lds((gas_p)(s3+dOff1), (las_p)(d+12288+dOff1), 16,0,0); \
    __builtin_amdgcn_global_load_lds((gas_p)(s3+dOff2), (las_p)(d+12288+dOff2), 16,0,0); \
  } while (0)

  // kt-invariant swizzled frag-read offsets (shorts)
  int offAhi[4], offAlo[4], offBhi[4], offBlo[4];
  #pragma unroll
  for (int mt = 0; mt < 4; mt++) {
    const int r = wm*64 + mt*16 + l15;
    offAhi[mt] = POFF(r, quad);
    offAlo[mt] = 4096 + POFF(r, quad);
  }
  #pragma unroll
  for (int g = 0; g < 4; g++) {
    const int r = g*32 + wn*16 + l15;
    offBhi[g] = 8192  + POFF(r, quad);
    offBlo[g] = 12288 + POFF(r, quad);
  }

  DMA_TILE(0, 0);

  #pragma unroll 1
  for (int kt = 0; kt < HID/BK; kt++) {
    const int sb = (kt & 1) * 16384;
    __syncthreads();                       // drains vmcnt -> tile kt resident
    if (kt + 1 < HID/BK) DMA_TILE(kt + 1, (kt + 1) & 1);   // flies during compute

    bf16x8 ah[4], al[4], bh[4], bl[4];
    #pragma unroll
    for (int mt = 0; mt < 4; mt++) {
      ah[mt] = *reinterpret_cast<const bf16x8*>(&lds[sb + offAhi[mt]]);
      al[mt] = *reinterpret_cast<const bf16x8*>(&lds[sb + offAlo[mt]]);
    }
    #pragma unroll
    for (int g = 0; g < 4; g++) {
      bh[g] = *reinterpret_cast<const bf16x8*>(&lds[sb + offBhi[g]]);
      bl[g] = *reinterpret_cast<const bf16x8*>(&lds[sb + offBlo[g]]);
    }
    #pragma unroll
    for (int g = 0; g < 4; g++)
      #pragma unroll
      for (int mt = 0; mt < 4; mt++)
        acc[g][mt] = __builtin_amdgcn_mfma_f32_16x16x32_bf16(ah[mt], bh[g], acc[g][mt], 0, 0, 0);
    #pragma unroll
    for (int g = 0; g < 4; g++)
      #pragma unroll
      for (int mt = 0; mt < 4; mt++)
        acc[g][mt] = __builtin_amdgcn_mfma_f32_16x16x32_bf16(al[mt], bh[g], acc[g][mt], 0, 0, 0);
    #pragma unroll
    for (int g = 0; g < 4; g++)
      #pragma unroll
      for (int mt = 0; mt < 4; mt++)
        acc[g][mt] = __builtin_amdgcn_mfma_f32_16x16x32_bf16(ah[mt], bl[g], acc[g][mt], 0, 0, 0);
  }

  // Epilogue: fused LSTM cell. C/D layout: col = lane&15, row = quad*4 + reg.
  const int fl = *flag;
  const int j = n0 + wn*16 + l15;
  float bi[4], m0v[4], m1v[4];
  #pragma unroll
  for (int g = 0; g < 4; g++) {
    bi[g]  = Beff[g*HID + j];
    m0v[g] = M0[g*HID + j];
    m1v[g] = M1[g*HID + j];
  }
  const int jq = (j >> 3) & 3;   // k-chunk of col j in next step's packed h
  #pragma unroll
  for (int mt = 0; mt < 4; mt++) {
    #pragma unroll
    for (int r = 0; r < 4; r++) {
      const int bl7 = wm*64 + mt*16 + quad*4 + r;   // b & 127
      const int b   = mb*BM + bl7;
      const long oidx = ((long)t_step * B_SZ + b) * 2;
      const float o0 = rdv(obs_raw, oidx, fl);
      const float o1 = rdv(obs_raw, oidx + 1, fl);
      const size_t off = (size_t)b*HID + j;
      float pi = acc[0][mt][r] + o0*m0v[0] + o1*m1v[0] + bi[0];
      float pf = acc[1][mt][r] + o0*m0v[1] + o1*m1v[1] + bi[1];
      float pg = acc[2][mt][r] + o0*m0v[2] + o1*m1v[2] + bi[2];
      float po = acc[3][mt][r] + o0*m0v[3] + o1*m1v[3] + bi[3];
      float cn = sigm(pf)*c_state[off] + sigm(pi)*tanh_f(pg);
      float hn = sigm(po)*tanh_f(cn);
      c_state[off] = cn;
      if (is_final) {
        if (fl) ((float*)out_final)[off] = hn;
        else    ((ushort*)out_final)[off] = f2bf(hn);
      } else {
        const long hpo = ((long)mb*32 + (j >> 5))*4096 + POFF(bl7, jq) + (j & 7);
        ushort hi = f2bf(hn);
        hout_hi[hpo] = hi;
        hout_lo[hpo] = f2bf(hn - bf2f(hi));
      }
    }
  }
}

extern "C" void kernel_launch(void* const* d_in, const int* in_sizes, int n_in,
                              void* d_out, int out_size, void* d_ws, size_t ws_size,
                              hipStream_t stream) {
  const void* obs  = d_in[0];
  const void* h0   = d_in[1];
  const void* c0   = d_in[2];
  const void* Wemb = d_in[3];
  const void* bemb = d_in[4];
  const void* Wih  = d_in[5];
  const void* Whh  = d_in[6];
  const void* bih  = d_in[7];
  const void* bhh  = d_in[8];

  char* w = (char*)d_ws;
  int*    flag    = (int*)w;
  float*  M0      = (float*)(w + 256);
  float*  M1      = M0 + G4;
  float*  Beff    = M1 + G4;
  float*  c_state = Beff + G4;                              // 8 MB
  ushort* wpk     = (ushort*)(c_state + (size_t)B_SZ*HID);  // 16 MB packed W (hi+lo)
  ushort* hAhi    = wpk + 2L*G4*HID;                        // 4 MB
  ushort* hAlo    = hAhi + (size_t)B_SZ*HID;                // 4 MB
  ushort* hBhi    = hAlo + (size_t)B_SZ*HID;                // 4 MB
  ushort* hBlo    = hBhi + (size_t)B_SZ*HID;                // 4 MB  (~40 MB total)

  detect_dtype<<<1, 1, 0, stream>>>((const ushort*)h0, flag);

  long totalCanon = 2L*B_SZ*HID + (long)G4*HID;
  canon<<<(int)((totalCanon + 255)/256), 256, 0, stream>>>(
      h0, c0, Whh, flag, hAhi, hAlo, c_state, wpk);

  fold_emb<<<G4, 64, 0, stream>>>(Wih, Wemb, bemb, bih, bhh, flag, M0, M1, Beff);

  for (int t = 0; t < T_LEN; t++) {
    const ushort* ih = (t & 1) ? hBhi : hAhi;
    const ushort* il = (t & 1) ? hBlo : hAlo;
    ushort* oh = (t & 1) ? hAhi : hBhi;
    ushort* ol = (t & 1) ? hAlo : hBlo;
    lstm_step<<<512, 256, 0, stream>>>(ih, il, oh, ol, d_out, c_state,
                                       wpk, M0, M1, Beff,
                                       obs, t, flag, (t == T_LEN - 1) ? 1 : 0);
  }
}

// Round 8
// 1078.129 us; speedup vs baseline: 1.9839x; 1.0169x over previous
//
#include <hip/hip_runtime.h>

#define B_SZ 2048
#define HID  1024
#define G4   4096
#define IN_D 512
#define T_LEN 20
#define BM 128
#define BK 32

// Swizzled offset of element (row r, k-chunk q) inside a 128x32 packed tile.
// 16B chunk q stored at position q ^ ((r>>1)&3): per 16-lane phase the b128
// frag reads land on 8 banks x 2-way (free, m136); DMA writes stay linear.
#define POFF(r, q) ((r)*32 + ((((q) ^ (((r) >> 1) & 3))) << 3))

typedef __attribute__((ext_vector_type(8))) short bf16x8;
typedef __attribute__((ext_vector_type(4))) float f32x4;
typedef const __attribute__((address_space(1))) void* gas_p;
typedef __attribute__((address_space(3))) void* las_p;

__device__ __forceinline__ float bf2f(ushort u){
  union { unsigned int i; float f; } v; v.i = ((unsigned int)u) << 16; return v.f;
}
__device__ __forceinline__ ushort f2bf(float f){
  union { float f; unsigned int i; } v; v.f = f;
  unsigned int r = v.i + 0x7fffu + ((v.i >> 16) & 1u);
  return (ushort)(r >> 16);
}
__device__ __forceinline__ float rdv(const void* p, long idx, int fl){
  return fl ? ((const float*)p)[idx] : bf2f(((const ushort*)p)[idx]);
}
__device__ __forceinline__ float sigm(float x){ return 1.0f/(1.0f + __expf(-x)); }
__device__ __forceinline__ float tanh_f(float x){
  float e = __expf(2.0f*x);
  return 1.0f - 2.0f/(e + 1.0f);
}

// flag=1 -> fp32 inputs; flag=0 -> bf16. Even ushorts of LE fp32 are low mantissa
// halves -> random bf16 exponents.
__global__ void detect_dtype(const ushort* __restrict__ h0bits, int* __restrict__ flag){
  int weird = 0;
  for (int i = 0; i < 256; i += 2){
    float a = fabsf(bf2f(h0bits[i]));
    if (!(a >= 1e-8f && a <= 1e4f)) weird++;
  }
  *flag = (weird >= 32) ? 1 : 0;
}

// Packed+swizzled layouts (every wave-level access = dense 1KB span; frag reads 2-way max):
//   h: tile (mb*32+kt) of 4096 shorts, element (b&127, j&31) at POFF
//   W: tiles (nb*32+kt)*2 {hi,lo} of 4096 shorts, row r = g*32+(j&31)
__global__ void canon(const void* __restrict__ h0, const void* __restrict__ c0,
                      const void* __restrict__ whh, const int* __restrict__ flag,
                      ushort* __restrict__ hAhi, ushort* __restrict__ hAlo,
                      float* __restrict__ c_state,
                      ushort* __restrict__ wpk){
  const int fl = *flag;
  long i = (long)blockIdx.x * 256 + threadIdx.x;
  const long N1 = (long)B_SZ * HID;
  const long N3 = (long)G4 * HID;
  if (i < N1){
    const int b = (int)(i >> 10), j = (int)(i & 1023);
    const int r = b & 127, q = (j >> 3) & 3;
    const long po = ((long)(b >> 7)*32 + (j >> 5))*4096 + POFF(r, q) + (j & 7);
    float x = rdv(h0, i, fl);
    ushort hi = f2bf(x);
    hAhi[po] = hi; hAlo[po] = f2bf(x - bf2f(hi));
    return;
  }
  i -= N1;
  if (i < N1){ c_state[i] = rdv(c0, i, fl); return; }
  i -= N1;
  if (i < N3){
    const int n = (int)(i >> 10), k = (int)(i & 1023);
    const int g = n >> 10, j = n & 1023;
    const int nb = j >> 5, r = g*32 + (j & 31);
    const int kt = k >> 5, q = (k >> 3) & 3;
    const long base = ((long)(nb*32 + kt)*2)*4096 + POFF(r, q) + (k & 7);
    float x = rdv(whh, i, fl);
    ushort hi = f2bf(x);
    wpk[base] = hi; wpk[base + 4096] = f2bf(x - bf2f(hi));
  }
}

// Fold embedding + input GEMM + biases into exact rank-2 update:
// gates_x[t,b,n] = obs[t,b,0]*M0[n] + obs[t,b,1]*M1[n] + Beff[n]
__global__ void fold_emb(const void* __restrict__ Wih, const void* __restrict__ Wemb,
                         const void* __restrict__ bemb, const void* __restrict__ bih,
                         const void* __restrict__ bhh, const int* __restrict__ flag,
                         float* __restrict__ M0, float* __restrict__ M1, float* __restrict__ Beff){
  const int n = blockIdx.x;
  const int lane = threadIdx.x;
  const int fl = *flag;
  float s0 = 0.f, s1 = 0.f, sb = 0.f;
  for (int j = lane; j < IN_D; j += 64){
    float w  = rdv(Wih, (long)n*IN_D + j, fl);
    float e0 = rdv(Wemb, 2L*j, fl);
    float e1 = rdv(Wemb, 2L*j + 1, fl);
    float be = rdv(bemb, j, fl);
    s0 += w*e0; s1 += w*e1; sb += w*be;
  }
  #pragma unroll
  for (int off = 32; off > 0; off >>= 1){
    s0 += __shfl_down(s0, off, 64);
    s1 += __shfl_down(s1, off, 64);
    sb += __shfl_down(sb, off, 64);
  }
  if (lane == 0){
    M0[n] = s0; M1[n] = s1;
    Beff[n] = sb + rdv(bih, n, fl) + rdv(bhh, n, fl);
  }
}

// Split-precision gates = h@W_hh^T: acc = h_hi*W_hi + h_lo*W_hi + h_hi*W_lo.
// A/B DMA'd to LDS (global_load_lds w=16), double-buffered, one barrier/iter.
// XCD-LOCAL h: mb = (bid&7)|((bid>>3)&1)<<3, nb = bid>>4 -> under bid%8
// round-robin, XCD x hosts mbs {x,x+8} x all nb: h[mb] producers==consumers
// on one XCD (h+c stay in local L2 across all 20 steps; the serialized
// recurrence path never crosses XCDs). W streams from L3 (clean, read-only,
// prefetched a full compute phase ahead).
__global__ __launch_bounds__(256, 2)
void lstm_step(const ushort* __restrict__ hin_hi, const ushort* __restrict__ hin_lo,
               ushort* __restrict__ hout_hi, ushort* __restrict__ hout_lo,
               void* __restrict__ out_final,
               float* __restrict__ c_state,
               const ushort* __restrict__ wpk,
               const float* __restrict__ M0, const float* __restrict__ M1,
               const float* __restrict__ Beff,
               const void* __restrict__ obs_raw, int t_step,
               const int* __restrict__ flag, int is_final)
{
  // [buf][region][4096]: regions 0=Ahi 1=Alo 2=Bhi 3=Blo; 64 KB total
  __shared__ __align__(16) ushort lds[2*4*4096];

  const int tid  = threadIdx.x;
  const int wave = tid >> 6;
  const int lane = tid & 63;
  const int l15  = lane & 15;
  const int quad = lane >> 4;
  const int wm   = wave & 1;    // M half (64 rows)
  const int wn   = wave >> 1;   // N half (16 cols of each gate)

  const int bid  = blockIdx.x;
  const int mb   = (bid & 7) | (((bid >> 3) & 1) << 3);   // XCD-local mb pair
  const int nb   = bid >> 4;                              // 0..31
  const int n0   = nb * 32;

  f32x4 acc[4][4];
  #pragma unroll
  for (int g = 0; g < 4; g++)
    #pragma unroll
    for (int mt = 0; mt < 4; mt++)
      acc[g][mt] = (f32x4){0.f, 0.f, 0.f, 0.f};

  const ushort* aHiB = hin_hi + (size_t)mb*32*4096;
  const ushort* aLoB = hin_lo + (size_t)mb*32*4096;
  const ushort* wB   = wpk + (size_t)nb*32*8192;

  const int dOff1 = wave*512 + lane*8;   // shorts: slot 'wave' of 8x1KB region
  const int dOff2 = dOff1 + 2048;        // slot wave+4

  #define DMA_TILE(kt, buf) do {                                              \
    const ushort* s0 = aHiB + (kt)*4096;                                      \
    const ushort* s1 = aLoB + (kt)*4096;                                      \
    const ushort* s2 = wB + (size_t)(kt)*8192;                                \
    const ushort* s3 = s2 + 4096;                                             \
    ushort* d = &lds[(buf)*16384];                                            \
    __builtin_amdgcn_global_load_lds((gas_p)(s0+dOff1), (las_p)(d+dOff1),       16,0,0); \
    __builtin_amdgcn_global_load_lds((gas_p)(s0+dOff2), (las_p)(d+dOff2),       16,0,0); \
    __builtin_amdgcn_global_load_lds((gas_p)(s1+dOff1), (las_p)(d+4096+dOff1),  16,0,0); \
    __builtin_amdgcn_global_load_lds((gas_p)(s1+dOff2), (las_p)(d+4096+dOff2),  16,0,0); \
    __builtin_amdgcn_global_load_lds((gas_p)(s2+dOff1), (las_p)(d+8192+dOff1),  16,0,0); \
    __builtin_amdgcn_global_load_lds((gas_p)(s2+dOff2), (las_p)(d+8192+dOff2),  16,0,0); \
    __builtin_amdgcn_global_load_lds((gas_p)(s3+dOff1), (las_p)(d+12288+dOff1), 16,0,0); \
    __builtin_amdgcn_global_load_lds((gas_p)(s3+dOff2), (las_p)(d+12288+dOff2), 16,0,0); \
  } while (0)

  // kt-invariant swizzled frag-read offsets (shorts)
  int offAhi[4], offAlo[4], offBhi[4], offBlo[4];
  #pragma unroll
  for (int mt = 0; mt < 4; mt++) {
    const int r = wm*64 + mt*16 + l15;
    offAhi[mt] = POFF(r, quad);
    offAlo[mt] = 4096 + POFF(r, quad);
  }
  #pragma unroll
  for (int g = 0; g < 4; g++) {
    const int r = g*32 + wn*16 + l15;
    offBhi[g] = 8192  + POFF(r, quad);
    offBlo[g] = 12288 + POFF(r, quad);
  }

  DMA_TILE(0, 0);

  #pragma unroll 1
  for (int kt = 0; kt < HID/BK; kt++) {
    const int sb = (kt & 1) * 16384;
    __syncthreads();                       // drains vmcnt -> tile kt resident
    if (kt + 1 < HID/BK) DMA_TILE(kt + 1, (kt + 1) & 1);   // flies during compute

    bf16x8 ah[4], al[4], bh[4], bl[4];
    #pragma unroll
    for (int mt = 0; mt < 4; mt++) {
      ah[mt] = *reinterpret_cast<const bf16x8*>(&lds[sb + offAhi[mt]]);
      al[mt] = *reinterpret_cast<const bf16x8*>(&lds[sb + offAlo[mt]]);
    }
    #pragma unroll
    for (int g = 0; g < 4; g++) {
      bh[g] = *reinterpret_cast<const bf16x8*>(&lds[sb + offBhi[g]]);
      bl[g] = *reinterpret_cast<const bf16x8*>(&lds[sb + offBlo[g]]);
    }
    #pragma unroll
    for (int g = 0; g < 4; g++)
      #pragma unroll
      for (int mt = 0; mt < 4; mt++)
        acc[g][mt] = __builtin_amdgcn_mfma_f32_16x16x32_bf16(ah[mt], bh[g], acc[g][mt], 0, 0, 0);
    #pragma unroll
    for (int g = 0; g < 4; g++)
      #pragma unroll
      for (int mt = 0; mt < 4; mt++)
        acc[g][mt] = __builtin_amdgcn_mfma_f32_16x16x32_bf16(al[mt], bh[g], acc[g][mt], 0, 0, 0);
    #pragma unroll
    for (int g = 0; g < 4; g++)
      #pragma unroll
      for (int mt = 0; mt < 4; mt++)
        acc[g][mt] = __builtin_amdgcn_mfma_f32_16x16x32_bf16(ah[mt], bl[g], acc[g][mt], 0, 0, 0);
  }

  // Epilogue: fused LSTM cell. C/D layout: col = lane&15, row = quad*4 + reg.
  const int fl = *flag;
  const int j = n0 + wn*16 + l15;
  float bi[4], m0v[4], m1v[4];
  #pragma unroll
  for (int g = 0; g < 4; g++) {
    bi[g]  = Beff[g*HID + j];
    m0v[g] = M0[g*HID + j];
    m1v[g] = M1[g*HID + j];
  }
  const int jq = (j >> 3) & 3;   // k-chunk of col j in next step's packed h
  #pragma unroll
  for (int mt = 0; mt < 4; mt++) {
    #pragma unroll
    for (int r = 0; r < 4; r++) {
      const int bl7 = wm*64 + mt*16 + quad*4 + r;   // b & 127
      const int b   = mb*BM + bl7;
      const long oidx = ((long)t_step * B_SZ + b) * 2;
      const float o0 = rdv(obs_raw, oidx, fl);
      const float o1 = rdv(obs_raw, oidx + 1, fl);
      const size_t off = (size_t)b*HID + j;
      float pi = acc[0][mt][r] + o0*m0v[0] + o1*m1v[0] + bi[0];
      float pf = acc[1][mt][r] + o0*m0v[1] + o1*m1v[1] + bi[1];
      float pg = acc[2][mt][r] + o0*m0v[2] + o1*m1v[2] + bi[2];
      float po = acc[3][mt][r] + o0*m0v[3] + o1*m1v[3] + bi[3];
      float cn = sigm(pf)*c_state[off] + sigm(pi)*tanh_f(pg);
      float hn = sigm(po)*tanh_f(cn);
      c_state[off] = cn;
      if (is_final) {
        if (fl) ((float*)out_final)[off] = hn;
        else    ((ushort*)out_final)[off] = f2bf(hn);
      } else {
        const long hpo = ((long)mb*32 + (j >> 5))*4096 + POFF(bl7, jq) + (j & 7);
        ushort hi = f2bf(hn);
        hout_hi[hpo] = hi;
        hout_lo[hpo] = f2bf(hn - bf2f(hi));
      }
    }
  }
}

extern "C" void kernel_launch(void* const* d_in, const int* in_sizes, int n_in,
                              void* d_out, int out_size, void* d_ws, size_t ws_size,
                              hipStream_t stream) {
  const void* obs  = d_in[0];
  const void* h0   = d_in[1];
  const void* c0   = d_in[2];
  const void* Wemb = d_in[3];
  const void* bemb = d_in[4];
  const void* Wih  = d_in[5];
  const void* Whh  = d_in[6];
  const void* bih  = d_in[7];
  const void* bhh  = d_in[8];

  char* w = (char*)d_ws;
  int*    flag    = (int*)w;
  float*  M0      = (float*)(w + 256);
  float*  M1      = M0 + G4;
  float*  Beff    = M1 + G4;
  float*  c_state = Beff + G4;                              // 8 MB
  ushort* wpk     = (ushort*)(c_state + (size_t)B_SZ*HID);  // 16 MB packed W (hi+lo)
  ushort* hAhi    = wpk + 2L*G4*HID;                        // 4 MB
  ushort* hAlo    = hAhi + (size_t)B_SZ*HID;                // 4 MB
  ushort* hBhi    = hAlo + (size_t)B_SZ*HID;                // 4 MB
  ushort* hBlo    = hBhi + (size_t)B_SZ*HID;                // 4 MB  (~40 MB total)

  detect_dtype<<<1, 1, 0, stream>>>((const ushort*)h0, flag);

  long totalCanon = 2L*B_SZ*HID + (long)G4*HID;
  canon<<<(int)((totalCanon + 255)/256), 256, 0, stream>>>(
      h0, c0, Whh, flag, hAhi, hAlo, c_state, wpk);

  fold_emb<<<G4, 64, 0, stream>>>(Wih, Wemb, bemb, bih, bhh, flag, M0, M1, Beff);

  for (int t = 0; t < T_LEN; t++) {
    const ushort* ih = (t & 1) ? hBhi : hAhi;
    const ushort* il = (t & 1) ? hBlo : hAlo;
    ushort* oh = (t & 1) ? hAhi : hBhi;
    ushort* ol = (t & 1) ? hAlo : hBlo;
    lstm_step<<<512, 256, 0, stream>>>(ih, il, oh, ol, d_out, c_state,
                                       wpk, M0, M1, Beff,
                                       obs, t, flag, (t == T_LEN - 1) ? 1 : 0);
  }
}